// Round 4
// baseline (293.272 us; speedup 1.0000x reference)
//
#include <hip/hip_runtime.h>
#include <math.h>

// NoisyTopkRouter: B=8,S=4096,D=1024,E=64,k=2  (M=32768 tokens)
// R9: wave-autonomous GEMM. No LDS staging, no K-loop barriers.
//  - Each wave owns a 32tok x 32col tile; K=1024 as 64 steps of 16 (one MFMA set).
//  - A fragments loaded DIRECTLY global->regs (lane row=l&31 reads 8 consecutive
//    floats at k = s*16 + oct*8), fp32->fp16 hi/lo split in regs (same ops as R5-R8).
//  - B from prep_B image: per (tile,row) 32 halves laid out [hi_o0|lo_o0|hi_o1|lo_o1]
//    so each lane reads 32B contiguous. No swizzle needed (no LDS).
//  - 2-step software pipeline with NAMED register sets (E/O), unrolled x2.
//  - Block = 4 waves = 32 tok x 128 cols (waves share A lines via L1/L2).
//    Grid = 1024 blocks = 4 blocks/CU = 16 independent waves/CU.
//  - Epilogue: Cs tile in LDS (17KB), one barrier, then verified R5-R8 math verbatim.
//  - Accumulation order per acc identical to R5-R8 -> absmax exactly 0.00390625.

#define DIM 1024
#define NEXP 64
#define CS 132
#define LOSCALE 2048.0f
#define INV_LOSCALE (1.0f / 2048.0f)

using half8v   = __attribute__((ext_vector_type(8)))  _Float16;
using floatx16 = __attribute__((ext_vector_type(16))) float;

#define MFMA32(a, b, c) __builtin_amdgcn_mfma_f32_32x32x16_f16((a), (b), (c), 0, 0, 0)

// ---------------- prep: split weights to fp16 hi/lo tile image ---------------------
// Image: [tile t=0..63][row r=0..127][32 halves: hi_o0(8) lo_o0(8) hi_o1(8) lo_o1(8)]
// Row r 0..63 = Wl experts, 64..127 = Wn.  tile t covers k = t*16..t*16+16.
__global__ __launch_bounds__(512)
void prep_B(const float* __restrict__ Wl, const float* __restrict__ Wn,
            _Float16* __restrict__ Bp)
{
    const int idx = blockIdx.x * 512 + threadIdx.x;   // 16384 threads
    const int r  = idx >> 7;        // 0..127
    const int c2 = idx & 127;       // 8-float chunk across K=1024
    const float* W = (r < 64) ? (Wl + (size_t)r * DIM) : (Wn + (size_t)(r - 64) * DIM);
    float f[8];
    *(float4*)(f)     = *(const float4*)(W + c2 * 8);
    *(float4*)(f + 4) = *(const float4*)(W + c2 * 8 + 4);
    half8v hi, lo;
#pragma unroll
    for (int i = 0; i < 8; i++) {
        _Float16 hh = (_Float16)f[i];
        hi[i] = hh;
        lo[i] = (_Float16)((f[i] - (float)hh) * LOSCALE);
    }
    const int t = c2 >> 1, hf = c2 & 1;               // tile, oct-half
    _Float16* base = Bp + ((size_t)t * 128 + r) * 32 + hf * 16;
    *(half8v*)(base)     = hi;
    *(half8v*)(base + 8) = lo;
}

// ---------------- main fused kernel ------------------------------------------------
__global__ __launch_bounds__(256, 4)
void router_fused(const float* __restrict__ h, const _Float16* __restrict__ Bp,
                  const float* __restrict__ bl, const float* __restrict__ bn,
                  const float* __restrict__ noise,
                  float* __restrict__ outR, float* __restrict__ outIx,
                  float* __restrict__ outF)
{
    __shared__ float Cs[32 * CS];            // 16896 B

    const int tid   = threadIdx.x;           // 0..255
    const int wv    = tid >> 6;              // 0..3  (column group)
    const int lane  = tid & 63;
    const int row31 = lane & 31;
    const int oct   = lane >> 5;
    const int colb  = wv * 32;               // 0,32,64,96
    const int tok0  = blockIdx.x * 32;

    // per-lane base pointers
    const float*    aP = h  + (size_t)(tok0 + row31) * DIM + oct * 8;
    const _Float16* bP = Bp + (size_t)(colb + row31) * 32 + oct * 16;
    // step strides: A += 16 floats; B += 128*32 = 4096 halves

    floatx16 acc1, acc2;
#pragma unroll
    for (int i = 0; i < 16; i++) { acc1[i] = 0.f; acc2[i] = 0.f; }

#define LOADA(s, A0, A1) do {                                                  \
        (A0) = *(const float4*)(aP + (s) * 16);                                \
        (A1) = *(const float4*)(aP + (s) * 16 + 4);                            \
    } while (0)
#define LOADB(s, BH, BL) do {                                                  \
        (BH) = *(const half8v*)(bP + (size_t)(s) * 4096);                      \
        (BL) = *(const half8v*)(bP + (size_t)(s) * 4096 + 8);                  \
    } while (0)
// split (exact ops of R5-R8) then 3 MFMA; acc order identical -> bit-identical
#define STEP(A0, A1, BH, BL) do {                                              \
        float f_[8] = {(A0).x, (A0).y, (A0).z, (A0).w,                         \
                       (A1).x, (A1).y, (A1).z, (A1).w};                        \
        half8v aH_, aL_;                                                       \
        _Pragma("unroll")                                                      \
        for (int i_ = 0; i_ < 8; i_++) {                                       \
            _Float16 hh_ = (_Float16)f_[i_];                                   \
            aH_[i_] = hh_;                                                     \
            aL_[i_] = (_Float16)((f_[i_] - (float)hh_) * LOSCALE);             \
        }                                                                      \
        acc1 = MFMA32(aH_, (BH), acc1);                                        \
        acc2 = MFMA32(aH_, (BL), acc2);                                        \
        acc2 = MFMA32(aL_, (BH), acc2);                                        \
    } while (0)

    // ---- 2-deep pipeline, named E/O register sets, 64 steps ----
    float4 aE0, aE1, aO0, aO1;
    half8v bHE, bLE, bHO, bLO;
    LOADA(0, aE0, aE1); LOADB(0, bHE, bLE);
    LOADA(1, aO0, aO1); LOADB(1, bHO, bLO);

    for (int tb = 0; tb < 31; ++tb) {
        const int s = 2 * tb;
        STEP(aE0, aE1, bHE, bLE);
        LOADA(s + 2, aE0, aE1); LOADB(s + 2, bHE, bLE);
        STEP(aO0, aO1, bHO, bLO);
        LOADA(s + 3, aO0, aO1); LOADB(s + 3, bHO, bLO);
    }
    STEP(aE0, aE1, bHE, bLE);                 // step 62
    STEP(aO0, aO1, bHO, bLO);                 // step 63

#undef STEP
#undef LOADB
#undef LOADA

    // ---- Cs: C layout col=lane&31, row=(reg&3)+8*(reg>>2)+4*oct (verified) ----
#pragma unroll
    for (int i = 0; i < 16; i++) {
        const int rowt = (i & 3) + 8 * (i >> 2) + 4 * oct;
        Cs[rowt * CS + colb + row31] = acc1[i] + acc2[i] * INV_LOSCALE;
    }
    __syncthreads();

    // ---- fused epilogue: lane = expert; 8 tokens per wave (verified R1-R8) ----
    const float blv = bl[lane];
    const float bnv = bn[lane];

    for (int t = wv; t < 32; t += 4) {
        const int gt = tok0 + t;
        float xr = Cs[t * CS + lane] + blv;
        float xf = Cs[t * CS + 64 + lane] + bnv;
        float nz = noise[(size_t)gt * NEXP + lane];

        // softplus (matches jax.nn.softplus)
        float stdv = fmaxf(xf, 0.f) + log1pf(expf(-fabsf(xf)));
        float noisy = fmaf(nz, stdv, xr);

        // merged max + argmax#1 (ties -> lowest index, matching lax.top_k)
        float v = noisy; int idx = lane;
#pragma unroll
        for (int o = 32; o > 0; o >>= 1) {
            float ov = __shfl_xor(v, o, 64);
            int   oi = __shfl_xor(idx, o, 64);
            if (ov > v || (ov == v && oi < idx)) { v = ov; idx = oi; }
        }
        const float v1 = v; const int i1 = idx;

        // full softmax over 64 lanes (max == v1)
        float p = expf(noisy - v1);
        float s = p;
#pragma unroll
        for (int o = 32; o > 0; o >>= 1) s += __shfl_xor(s, o, 64);
        float fullp = p / s;

        // argmax #2
        v = (lane == i1) ? -INFINITY : noisy; idx = lane;
#pragma unroll
        for (int o = 32; o > 0; o >>= 1) {
            float ov = __shfl_xor(v, o, 64);
            int   oi = __shfl_xor(idx, o, 64);
            if (ov > v || (ov == v && oi < idx)) { v = ov; idx = oi; }
        }
        const float v2 = v; const int i2 = idx;

        // sparse softmax over {i1,i2}
        float e2 = expf(v2 - v1);
        float den = 1.f + e2;
        float routep = (lane == i1) ? (1.f / den) : ((lane == i2) ? (e2 / den) : 0.f);

        outR[(size_t)gt * NEXP + lane] = routep;
        outF[(size_t)gt * NEXP + lane] = fullp;
        if (lane == 0) {
            outIx[(size_t)gt * 2 + 0] = (float)i1;
            outIx[(size_t)gt * 2 + 1] = (float)i2;
        }
    }
}

extern "C" void kernel_launch(void* const* d_in, const int* in_sizes, int n_in,
                              void* d_out, int out_size, void* d_ws, size_t ws_size,
                              hipStream_t stream) {
    const float* h     = (const float*)d_in[0];
    const float* Wl    = (const float*)d_in[1];
    const float* bl    = (const float*)d_in[2];
    const float* Wn    = (const float*)d_in[3];
    const float* bn    = (const float*)d_in[4];
    const float* noise = (const float*)d_in[5];
    float* out = (float*)d_out;

    const int M = in_sizes[0] / DIM;                 // 32768
    float* outR  = out;                              // [M,64]
    float* outIx = out + (size_t)M * NEXP;           // [M,2]
    float* outF  = outIx + (size_t)M * 2;            // [M,64]

    _Float16* Bp = (_Float16*)d_ws;                  // 512 KiB tile image

    prep_B<<<32, 512, 0, stream>>>(Wl, Wn, Bp);
    router_fused<<<M / 32, 256, 0, stream>>>(h, Bp, bl, bn, noise, outR, outIx, outF);
}

// Round 6
// 252.571 us; speedup vs baseline: 1.1611x; 1.1611x over previous
//
#include <hip/hip_runtime.h>
#include <math.h>

// NoisyTopkRouter: B=8,S=4096,D=1024,E=64,k=2  (M=32768 tokens)
// R10b: R10 with the double-buffer parity bug fixed.
//   Tile t lives in buf[t&1]; R10 selected the compute buffer by (t0&2) [tb
//   parity] which read the WRONG buffer for half the K-tiles -> absmax 468.
//   Fix: static parity -- even t: compute buf0 / write buf1; odd t: compute
//   buf1 / write buf0. Everything else identical to R10.
//  - Block = 32 tok x 128 col, 256 thr = 4 waves, each wave one 32x32 tile.
//    Grid = 1024 blocks = 4 independent blocks/CU (16 waves/CU).
//  - K-step 64 per barrier -> 16 barriers, 12 MFMA per wave per barrier.
//  - Only A staged in LDS (shared by the 4 waves), fp32->fp16 hi/lo split ONCE
//    per element at stage. Rows 272B (odd*16) -> conflict-free b128, no swizzle.
//  - B read directly global->regs from prep_B image (L1/L2-resident, 32B/lane
//    contiguous), issued at iter top; VALU stage section + 4-way block overlap
//    covers the latency.
//  - K ascending in 16-steps, same 3-MFMA order (AhBh->acc1, AhBl->acc2,
//    AlBh->acc2) -> bit-identical to R5-R9 (absmax exactly 0.00390625).
//  - Epilogue verbatim (verified R1-R9).

#define DIM 1024
#define NEXP 64
#define CS 132
#define LOSCALE 2048.0f
#define INV_LOSCALE (1.0f / 2048.0f)
#define AROW 272              // bytes per A row in LDS (odd multiple of 16)
#define ABUF 8704             // 32 rows * 272

using half8v   = __attribute__((ext_vector_type(8)))  _Float16;
using floatx16 = __attribute__((ext_vector_type(16))) float;

#define MFMA32(a, b, c) __builtin_amdgcn_mfma_f32_32x32x16_f16((a), (b), (c), 0, 0, 0)

#define WAITLGKM0 asm volatile("s_waitcnt lgkmcnt(0)" ::: "memory")
#define SCHED0    __builtin_amdgcn_sched_barrier(0)
#define BAR       __builtin_amdgcn_s_barrier()

// ---------------- prep: split weights to fp16 hi/lo tile image ---------------------
// Image: [tile t=0..63][row r=0..127][32 halves: hi_o0(8) lo_o0(8) hi_o1(8) lo_o1(8)]
__global__ __launch_bounds__(512)
void prep_B(const float* __restrict__ Wl, const float* __restrict__ Wn,
            _Float16* __restrict__ Bp)
{
    const int idx = blockIdx.x * 512 + threadIdx.x;   // 16384 threads
    const int r  = idx >> 7;        // 0..127
    const int c2 = idx & 127;       // 8-float chunk across K=1024
    const float* W = (r < 64) ? (Wl + (size_t)r * DIM) : (Wn + (size_t)(r - 64) * DIM);
    float f[8];
    *(float4*)(f)     = *(const float4*)(W + c2 * 8);
    *(float4*)(f + 4) = *(const float4*)(W + c2 * 8 + 4);
    half8v hi, lo;
#pragma unroll
    for (int i = 0; i < 8; i++) {
        _Float16 hh = (_Float16)f[i];
        hi[i] = hh;
        lo[i] = (_Float16)((f[i] - (float)hh) * LOSCALE);
    }
    const int t = c2 >> 1, hf = c2 & 1;               // tile, oct-half
    _Float16* base = Bp + ((size_t)t * 128 + r) * 32 + hf * 16;
    *(half8v*)(base)     = hi;
    *(half8v*)(base + 8) = lo;
}

// ---------------- main fused kernel ------------------------------------------------
__global__ __launch_bounds__(256, 4)
void router_fused(const float* __restrict__ h, const _Float16* __restrict__ Bp,
                  const float* __restrict__ bl, const float* __restrict__ bn,
                  const float* __restrict__ noise,
                  float* __restrict__ outR, float* __restrict__ outIx,
                  float* __restrict__ outF)
{
    __shared__ __align__(16) char lds_raw[2 * ABUF];   // 17408 B; Cs needs 16896

    const int tid   = threadIdx.x;           // 0..255
    const int wv    = tid >> 6;              // 0..3  (column group)
    const int lane  = tid & 63;
    const int row31 = lane & 31;
    const int oct   = lane >> 5;
    const int colb  = wv * 32;               // 0,32,64,96
    const int tok0  = blockIdx.x * 32;

    // ---- A staging map: thread -> row rSt, 8-float group f8 of the 64-K tile ----
    const int rSt = tid >> 3, f8 = tid & 7;
    const float* aStage = h + (size_t)(tok0 + rSt) * DIM + f8 * 8;
    const int aWhi = rSt * AROW + f8 * 16;   // hi chunk byte offset; lo at +128

    // ---- B direct-read map (32B contiguous per lane per sub-step) ----
    const _Float16* bP = Bp + (size_t)(colb + row31) * 32 + oct * 16;

    // ---- A fragment read base ----
    const int rdHi = row31 * AROW;           // + (ss*2+oct)*16, lo +128

    floatx16 acc1, acc2;
#pragma unroll
    for (int i = 0; i < 16; i++) { acc1[i] = 0.f; acc2[i] = 0.f; }

#define LOADA(t, A0, A1) do {                                                  \
        (A0) = *(const float4*)(aStage + (t) * 64);                            \
        (A1) = *(const float4*)(aStage + (t) * 64 + 4);                        \
    } while (0)

#define SPLITW(bufc, A0, A1) do {                                              \
        float f_[8] = {(A0).x, (A0).y, (A0).z, (A0).w,                         \
                       (A1).x, (A1).y, (A1).z, (A1).w};                        \
        half8v hi_, lo_;                                                       \
        _Pragma("unroll")                                                      \
        for (int i_ = 0; i_ < 8; i_++) {                                       \
            _Float16 hh_ = (_Float16)f_[i_];                                   \
            hi_[i_] = hh_;                                                     \
            lo_[i_] = (_Float16)((f_[i_] - (float)hh_) * LOSCALE);             \
        }                                                                      \
        *(half8v*)((bufc) + aWhi)       = hi_;                                 \
        *(half8v*)((bufc) + aWhi + 128) = lo_;                                 \
    } while (0)

#define ISSUE_B(t) do {                                                        \
        const _Float16* bs_ = bP + (size_t)(t) * 16384;                        \
        bh0 = *(const half8v*)(bs_);                                           \
        bl0 = *(const half8v*)(bs_ + 8);                                       \
        bh1 = *(const half8v*)(bs_ + 4096);                                    \
        bl1 = *(const half8v*)(bs_ + 4104);                                    \
        bh2 = *(const half8v*)(bs_ + 8192);                                    \
        bl2 = *(const half8v*)(bs_ + 8200);                                    \
        bh3 = *(const half8v*)(bs_ + 12288);                                   \
        bl3 = *(const half8v*)(bs_ + 12296);                                   \
    } while (0)

#define SUBSTEP(bufc, ss, BH, BL) do {                                         \
        const int co_ = ((ss) * 2 + oct) << 4;                                 \
        const half8v aH_ = *(const half8v*)((bufc) + rdHi + co_);              \
        const half8v aL_ = *(const half8v*)((bufc) + rdHi + co_ + 128);        \
        acc1 = MFMA32(aH_, (BH), acc1);                                        \
        acc2 = MFMA32(aH_, (BL), acc2);                                        \
        acc2 = MFMA32(aL_, (BH), acc2);                                        \
    } while (0)

#define COMPUTE(bufc) do {                                                     \
        SUBSTEP(bufc, 0, bh0, bl0);                                            \
        SUBSTEP(bufc, 1, bh1, bl1);                                            \
        SUBSTEP(bufc, 2, bh2, bl2);                                            \
        SUBSTEP(bufc, 3, bh3, bl3);                                            \
    } while (0)

    half8v bh0, bl0, bh1, bl1, bh2, bl2, bh3, bl3;
    char* const buf0 = lds_raw;
    char* const buf1 = lds_raw + ABUF;
    float4 aE0, aE1, aO0, aO1;

    // ---- prologue: tile0 -> buf0; tile1 -> O regs ----
    LOADA(0, aE0, aE1);
    SPLITW(buf0, aE0, aE1);
    LOADA(1, aO0, aO1);
    WAITLGKM0; SCHED0;
    BAR; SCHED0;

// iter t: ISSUE_B(t); split/write A(t+1); load A(t+2); compute(buf[t&1]); sync
#define BODY_W_L(t, CBUF, NBUF, AW0, AW1, AL0, AL1) do {                       \
        ISSUE_B(t);                                                            \
        SPLITW(NBUF, AW0, AW1);                                                \
        LOADA((t) + 2, AL0, AL1);                                              \
        COMPUTE(CBUF);                                                         \
        WAITLGKM0; SCHED0;                                                     \
        BAR; SCHED0;                                                           \
    } while (0)

    // t = 0..13 in parity pairs. Tile t lives in buf[t&1] (FIX vs R10):
    //   even t: compute buf0, write tile t+1 (O regs) -> buf1, load E
    //   odd  t: compute buf1, write tile t+1 (E regs) -> buf0, load O
    for (int tb = 0; tb < 7; ++tb) {
        const int t0 = 2 * tb;
        BODY_W_L(t0,     buf0, buf1, aO0, aO1, aE0, aE1);
        BODY_W_L(t0 + 1, buf1, buf0, aE0, aE1, aO0, aO1);
    }
    // t = 14 (even): write tile15 from O into buf1; no more A loads
    ISSUE_B(14);
    SPLITW(buf1, aO0, aO1);
    COMPUTE(buf0);
    WAITLGKM0; SCHED0;
    BAR; SCHED0;
    // t = 15: compute only
    ISSUE_B(15);
    COMPUTE(buf1);
    __syncthreads();                          // full drain before Cs overlay

#undef BODY_W_L
#undef COMPUTE
#undef SUBSTEP
#undef ISSUE_B
#undef SPLITW
#undef LOADA

    // ---- Cs: C layout col=lane&31, row=(reg&3)+8*(reg>>2)+4*oct (verified) ----
    float* Cs = (float*)lds_raw;
#pragma unroll
    for (int i = 0; i < 16; i++) {
        const int rowt = (i & 3) + 8 * (i >> 2) + 4 * oct;
        Cs[rowt * CS + colb + row31] = acc1[i] + acc2[i] * INV_LOSCALE;
    }
    __syncthreads();

    // ---- fused epilogue: lane = expert; 8 tokens per wave (verified R1-R9) ----
    const float blv = bl[lane];
    const float bnv = bn[lane];

    for (int t = wv; t < 32; t += 4) {
        const int gt = tok0 + t;
        float xr = Cs[t * CS + lane] + blv;
        float xf = Cs[t * CS + 64 + lane] + bnv;
        float nz = noise[(size_t)gt * NEXP + lane];

        // softplus (matches jax.nn.softplus)
        float stdv = fmaxf(xf, 0.f) + log1pf(expf(-fabsf(xf)));
        float noisy = fmaf(nz, stdv, xr);

        // merged max + argmax#1 (ties -> lowest index, matching lax.top_k)
        float v = noisy; int idx = lane;
#pragma unroll
        for (int o = 32; o > 0; o >>= 1) {
            float ov = __shfl_xor(v, o, 64);
            int   oi = __shfl_xor(idx, o, 64);
            if (ov > v || (ov == v && oi < idx)) { v = ov; idx = oi; }
        }
        const float v1 = v; const int i1 = idx;

        // full softmax over 64 lanes (max == v1)
        float p = expf(noisy - v1);
        float s = p;
#pragma unroll
        for (int o = 32; o > 0; o >>= 1) s += __shfl_xor(s, o, 64);
        float fullp = p / s;

        // argmax #2
        v = (lane == i1) ? -INFINITY : noisy; idx = lane;
#pragma unroll
        for (int o = 32; o > 0; o >>= 1) {
            float ov = __shfl_xor(v, o, 64);
            int   oi = __shfl_xor(idx, o, 64);
            if (ov > v || (ov == v && oi < idx)) { v = ov; idx = oi; }
        }
        const float v2 = v; const int i2 = idx;

        // sparse softmax over {i1,i2}
        float e2 = expf(v2 - v1);
        float den = 1.f + e2;
        float routep = (lane == i1) ? (1.f / den) : ((lane == i2) ? (e2 / den) : 0.f);

        outR[(size_t)gt * NEXP + lane] = routep;
        outF[(size_t)gt * NEXP + lane] = fullp;
        if (lane == 0) {
            outIx[(size_t)gt * 2 + 0] = (float)i1;
            outIx[(size_t)gt * 2 + 1] = (float)i2;
        }
    }
}

extern "C" void kernel_launch(void* const* d_in, const int* in_sizes, int n_in,
                              void* d_out, int out_size, void* d_ws, size_t ws_size,
                              hipStream_t stream) {
    const float* h     = (const float*)d_in[0];
    const float* Wl    = (const float*)d_in[1];
    const float* bl    = (const float*)d_in[2];
    const float* Wn    = (const float*)d_in[3];
    const float* bn    = (const float*)d_in[4];
    const float* noise = (const float*)d_in[5];
    float* out = (float*)d_out;

    const int M = in_sizes[0] / DIM;                 // 32768
    float* outR  = out;                              // [M,64]
    float* outIx = out + (size_t)M * NEXP;           // [M,2]
    float* outF  = outIx + (size_t)M * 2;            // [M,64]

    _Float16* Bp = (_Float16*)d_ws;                  // 512 KiB tile image

    prep_B<<<32, 512, 0, stream>>>(Wl, Wn, Bp);
    router_fused<<<M / 32, 256, 0, stream>>>(h, Bp, bl, bn, noise, outR, outIx, outF);
}